// Round 14
// baseline (335.988 us; speedup 1.0000x reference)
//
#include <hip/hip_runtime.h>
#include <stdint.h>

#define HW   1369      // 37*37 output pixels
#define QW   39        // padded row width
#define QP2  1648      // padded plane rows per (b) in Xp (1616 used + stage slack)
#define QT   1536      // q rows in x1 (per batch)
#define CIN  1024
#define CMID 512
#define NTIL 144       // K-tiles: 16 cblocks(64) * 9 taps, cblock-major tap-inner
#define PANEL 18432    // panel elements: 288 rows x 64 cols (36 KB)

typedef float  f32x4  __attribute__((ext_vector_type(4)));
typedef __bf16 bf16x8 __attribute__((ext_vector_type(8)));

__device__ __forceinline__ uint16_t f2bf(float f) {
  uint32_t u = __float_as_uint(f);
  u += 0x7fffu + ((u >> 16) & 1u);
  return (uint16_t)(u >> 16);
}

// global -> LDS direct copy, 16B per lane. LDS dest = wave-uniform base + lane*16.
__device__ __forceinline__ void gll16(const void* g, void* l) {
  const __attribute__((address_space(1))) uint32_t* ga =
      (const __attribute__((address_space(1))) uint32_t*)(uintptr_t)g;
  __attribute__((address_space(3))) uint32_t* la =
      (__attribute__((address_space(3))) uint32_t*)(uint32_t)(uintptr_t)l;
  __builtin_amdgcn_global_load_lds(ga, la, 16, 0, 0);
}

// ---------- prep: fmap [b][c][h][w] f32 -> Xp [b][q][c] bf16 (padded, zeroed border) ----------
__global__ void k_pad_transpose(const float* __restrict__ fmap, uint16_t* __restrict__ Xp) {
  __shared__ float t[32][33];
  const int b = blockIdx.z;
  const int c0 = blockIdx.y * 32;
  const int p0 = blockIdx.x * 32;
  const int tx = threadIdx.x, ty = threadIdx.y;
  const float* src = fmap + ((size_t)b * CIN + c0) * HW + p0;
#pragma unroll
  for (int i = 0; i < 4; ++i) {
    int cc = ty + i * 8;
    t[cc][tx] = (p0 + tx < HW) ? src[(size_t)cc * HW + tx] : 0.f;
  }
  __syncthreads();
#pragma unroll
  for (int i = 0; i < 4; ++i) {
    int pl = ty + i * 8;
    int p = p0 + pl;
    if (p < HW) {
      int h = p / 37, w = p - h * 37;
      int q = (h + 1) * QW + (w + 1);
      Xp[((size_t)b * QP2 + q) * CIN + c0 + tx] = f2bf(t[tx][pl]);
    }
  }
}

// ---------- prep: W1 -> B fragments in MFMA order (r12-verified, bit-identical) ----------
// Bp[frag][lane][8el], frag = (t*32 + o16)*2 + kk. Lane l holds
// B[o16*16 + (l&15)][tap*1024 + cb*64 + kk*32 + (l>>4)*8 ..+8], t = cb*9+tap.
__global__ void k_pack_bfrag(const float* __restrict__ W1, uint16_t* __restrict__ Bp) {
  const int gid = blockIdx.x * 256 + threadIdx.x;   // 589824 exact
  const int lane = gid & 63;
  const int f    = gid >> 6;
  const int kk   = f & 1;
  const int o16  = (f >> 1) & 31;
  const int t    = f >> 6;
  const int cb = t / 9, tap = t - cb * 9;
  const int o   = o16 * 16 + (lane & 15);
  const int kap = kk * 32 + (lane >> 4) * 8;
  uint16_t* dst = Bp + (size_t)gid * 8;
#pragma unroll
  for (int e = 0; e < 8; ++e) {
    const int c = cb * 64 + kap + e;
    dst[e] = f2bf(W1[((size_t)o * CIN + c) * 9 + tap]);
  }
}

// ---------- prep: W2 [120][512] f32 -> W2p [128][512] bf16 ----------
__global__ void k_pack_w2(const float* __restrict__ W2, uint16_t* __restrict__ W2p) {
  int idx = blockIdx.x * 256 + threadIdx.x;
  int j = idx >> 9, o = idx & 511;
  W2p[idx] = (j < 120) ? f2bf(W2[j * 512 + o]) : (uint16_t)0;
}

// ---------- conv1: tap-reuse A panel + frag-packed B, 9-tile barrier-free groups ----------
// Block 192x128, 4 waves 2M x 2N (wave 96x64), 512 blocks = 2 blocks/CU.
// A: per-cblock 288-row x 64-col panel (36KB) staged ONCE per 9 tiles via 9
//    gll16 calls spread 1/tile, double-buffered (72KB LDS). Taps read shifted
//    rows (off = (tap/3)*39 + tap%3) of the SAME panel -> writes amortized 9x.
// B: r12 frag-packed coalesced loads (C++ derefs; compiler emits counted vmcnt),
//    register ping-pong bvX/bvY prefetched 1 tile ahead.
// Sync: ONE vmcnt(0)+barrier per cblock GROUP (16 total). No barriers inside a
// group -> waves de-phase across 9 tiles; LDS reads overlap MFMA freely.
// LDS/CU/tile ~104KB (1224cyc) and VMEM ~72KB (~1125cyc) << MFMA 1862cyc.
__global__ __launch_bounds__(256, 2) void k_conv1(
    const uint16_t* __restrict__ Xp, const uint16_t* __restrict__ Bp,
    const float* __restrict__ b1, uint16_t* __restrict__ x1) {
  __shared__ __align__(16) uint16_t lds[2 * PANEL];   // 73728 B

  const int tid  = threadIdx.x;
  const int wid  = tid >> 6, lane = tid & 63;
  const int lrow = lane & 15, lq = lane >> 4;
  const int wm   = wid >> 1,  wn = wid & 1;           // 2M x 2N

  // grid: 512 blocks = 8 XCDs x 64, mt-major within XCD (4 nt consecutive)
  const int bid = blockIdx.x;
  const int g   = (bid & 7) * 64 + (bid >> 3);
  const int mt  = g >> 2, nt = g & 3;
  const int batch = mt >> 3, qb = (mt & 7) * 192;
  const int o0 = nt * 128;
  const uint16_t* Xb = Xp + (size_t)batch * QP2 * CIN;

  // panel staging: per call, wave w stages rows [call*32 + w*8, +8): 1KB contiguous.
  const int sR8  = lane >> 3;                       // 0..7 row-sub within wave
  const int sc8  = ((lane & 7) ^ sR8) * 8;          // pre-swizzled source col (elements)

  // B frag pointers (r12-verified)
  const uint16_t* Bpl = Bp + (size_t)lane * 8;
  const int o16b = nt * 8 + wn * 4;

  f32x4 acc[6][4] = {};
  bf16x8 bvX[8], bvY[8];

#define STPAN(cb1, call) do {                                                         \
    if ((cb1) < 16) {                                                                 \
      const int c0_ = (cb1) << 6;                                                     \
      const int Rb  = (call) * 32 + wid * 8;                                          \
      gll16(Xb + (size_t)(qb + Rb + sR8) * CIN + c0_ + sc8,                           \
            lds + ((cb1) & 1) * PANEL + Rb * 64);                                     \
    }                                                                                 \
  } while (0)

#define LOADB(u, BV) do {                                                             \
    if ((u) < NTIL) {                                                                 \
      _Pragma("unroll")                                                               \
      for (int n = 0; n < 4; ++n)                                                     \
        _Pragma("unroll")                                                             \
        for (int kk = 0; kk < 2; ++kk)                                                \
          BV[n * 2 + kk] = *(const bf16x8*)(                                          \
              Bpl + (((size_t)(u) * 32 + o16b + n) * 2 + kk) * 512);                  \
    }                                                                                 \
  } while (0)

  // one tile: read A frags (tap-shifted rows of the group panel), issue next-tile
  // B loads + one panel-stage call, then MFMA. No barriers, no manual lgkm/vmcnt:
  // compiler inserts counted waits for both ds_reads and B derefs.
#define TAP(tap, BVC, BVN) do {                                                       \
    const int off_ = ((tap) / 3) * QW + (tap) % 3;                                    \
    const int r7   = (off_ + lrow) & 7;                                               \
    const int ce0  = ((lq * 16) ^ (r7 << 4)) >> 1;                                    \
    const int ce1  = ce0 ^ 32;                                                        \
    bf16x8 av0[6], av1[6];                                                            \
    _Pragma("unroll")                                                                 \
    for (int m = 0; m < 6; ++m) {                                                     \
      const uint16_t* ar = pan + (off_ + wm * 96 + m * 16 + lrow) * 64;               \
      av0[m] = *(const bf16x8*)(ar + ce0);                                            \
      av1[m] = *(const bf16x8*)(ar + ce1);                                            \
    }                                                                                 \
    LOADB(cb * 9 + (tap) + 1, BVN);                                                   \
    STPAN(cb + 1, tap);                                                               \
    __builtin_amdgcn_s_setprio(1);                                                    \
    _Pragma("unroll")                                                                 \
    for (int m = 0; m < 6; ++m)                                                       \
      _Pragma("unroll")                                                               \
      for (int n = 0; n < 4; ++n)                                                     \
        acc[m][n] = __builtin_amdgcn_mfma_f32_16x16x32_bf16(                          \
            av0[m], BVC[n * 2], acc[m][n], 0, 0, 0);                                  \
    _Pragma("unroll")                                                                 \
    for (int m = 0; m < 6; ++m)                                                       \
      _Pragma("unroll")                                                               \
      for (int n = 0; n < 4; ++n)                                                     \
        acc[m][n] = __builtin_amdgcn_mfma_f32_16x16x32_bf16(                          \
            av1[m], BVC[n * 2 + 1], acc[m][n], 0, 0, 0);                              \
    __builtin_amdgcn_s_setprio(0);                                                    \
  } while (0)

#define GROUP(CB, B0, B1) do {                                                        \
    const int cb = (CB);                                                              \
    asm volatile("s_waitcnt vmcnt(0)" ::: "memory");  /* panel(cb) writes landed */   \
    asm volatile("s_barrier" ::: "memory");           /* all waves: publish + WAR */  \
    __builtin_amdgcn_sched_barrier(0);                                                \
    const uint16_t* pan = lds + (cb & 1) * PANEL;                                     \
    TAP(0, B0, B1); TAP(1, B1, B0); TAP(2, B0, B1);                                   \
    TAP(3, B1, B0); TAP(4, B0, B1); TAP(5, B1, B0);                                   \
    TAP(6, B0, B1); TAP(7, B1, B0); TAP(8, B0, B1);                                   \
  } while (0)

  // prologue: stage panel 0 (9 calls into buf 0) + B(0)
  for (int c = 0; c < 9; ++c) STPAN(0, c);
  LOADB(0, bvX);

  for (int cb2 = 0; cb2 < 16; cb2 += 2) {
    GROUP(cb2,     bvX, bvY);   // taps consume X,Y,X,Y,X,Y,X,Y,X ; tap8 loads Y
    GROUP(cb2 + 1, bvY, bvX);   // continues the chain
  }

  // epilogue: bias + ReLU6 -> x1 bf16
  const int qr = lq * 4;
#pragma unroll
  for (int n = 0; n < 4; ++n) {
    const int o = o0 + wn * 64 + n * 16 + lrow;
    const float bias = b1[o];
#pragma unroll
    for (int m = 0; m < 6; ++m) {
#pragma unroll
      for (int v = 0; v < 4; ++v) {
        const int q = qb + wm * 96 + m * 16 + qr + v;
        float x = acc[m][n][v] + bias;
        x = fminf(fmaxf(x, 0.f), 6.f);
        x1[((size_t)batch * QT + q) * CMID + o] = f2bf(x);
      }
    }
  }
#undef GROUP
#undef TAP
#undef LOADB
#undef STPAN
}

// ---------- conv2: out[b][h][w][j] = sum_o x1[q][o] * W2[j][o] + b2[j] ----------
__global__ __launch_bounds__(256, 2) void k_conv2(
    const uint16_t* __restrict__ x1, const uint16_t* __restrict__ W2p,
    const float* __restrict__ b2, float* __restrict__ out) {
  __shared__ __align__(16) uint16_t lA[128 * 64];
  __shared__ __align__(16) uint16_t lB[128 * 64];
  const int tid = threadIdx.x;
  const int wid = tid >> 6, lane = tid & 63;
  const int b = blockIdx.z, q0 = blockIdx.x * 128;
  const uint16_t* Ab = x1 + (size_t)b * QT * CMID;
  const int wm = wid >> 1, wn = wid & 1;
  const int lrow = lane & 15, lk = (lane >> 4) * 8;
  f32x4 acc[4][4] = {};

  for (int kt = 0; kt < 8; ++kt) {
    const int c0 = kt << 6;
#pragma unroll
    for (int i = 0; i < 4; ++i) {
      int wb = i * 256 + wid * 64;
      int chunk = wb + lane;
      int row = chunk >> 3, ch = chunk & 7;
      gll16(Ab + (size_t)(q0 + row) * CMID + c0 + ch * 8, lA + wb * 8);
      gll16(W2p + (size_t)row * CMID + c0 + ch * 8, lB + wb * 8);
    }
    __syncthreads();
#pragma unroll
    for (int kk = 0; kk < 2; ++kk) {
      bf16x8 av[4], bv[4];
#pragma unroll
      for (int mi = 0; mi < 4; ++mi)
        av[mi] = *(const bf16x8*)(lA + (wm * 64 + mi * 16 + lrow) * 64 + kk * 32 + lk);
#pragma unroll
      for (int ni = 0; ni < 4; ++ni)
        bv[ni] = *(const bf16x8*)(lB + (wn * 64 + ni * 16 + lrow) * 64 + kk * 32 + lk);
#pragma unroll
      for (int mi = 0; mi < 4; ++mi)
#pragma unroll
        for (int ni = 0; ni < 4; ++ni)
          acc[mi][ni] = __builtin_amdgcn_mfma_f32_16x16x32_bf16(av[mi], bv[ni], acc[mi][ni], 0, 0, 0);
    }
    __syncthreads();
  }

  const int qr = (lane >> 4) * 4;
#pragma unroll
  for (int ni = 0; ni < 4; ++ni) {
    int j = wn * 64 + ni * 16 + lrow;
    if (j < 120) {
      float bias = b2[j];
#pragma unroll
      for (int mi = 0; mi < 4; ++mi) {
#pragma unroll
        for (int v = 0; v < 4; ++v) {
          int q = q0 + wm * 64 + mi * 16 + qr + v;
          int h = q / QW, w = q - h * QW;
          if (h < 37 && w < 37) {
            out[((size_t)b * HW + h * 37 + w) * 120 + j] = acc[mi][ni][v] + bias;
          }
        }
      }
    }
  }
}

extern "C" void kernel_launch(void* const* d_in, const int* in_sizes, int n_in,
                              void* d_out, int out_size, void* d_ws, size_t ws_size,
                              hipStream_t stream) {
  const float* fmap = (const float*)d_in[0];
  const float* W1   = (const float*)d_in[1];
  const float* b1   = (const float*)d_in[2];
  const float* W2   = (const float*)d_in[3];
  const float* b2   = (const float*)d_in[4];
  float* out = (float*)d_out;

  uint8_t* ws = (uint8_t*)d_ws;
  const size_t XP_BYTES = (size_t)16 * QP2 * CIN * 2;         // 54,001,664
  const size_t BP_BYTES = (size_t)144 * 32 * 2 * 64 * 8 * 2;  //  9,437,184
  const size_t W2P_BYTES = (size_t)128 * 512 * 2;             //    131,072
  uint16_t* Xp  = (uint16_t*)ws;
  uint16_t* Bp  = (uint16_t*)(ws + XP_BYTES);
  uint16_t* W2p = (uint16_t*)(ws + XP_BYTES + BP_BYTES);
  uint16_t* x1  = (uint16_t*)(ws + XP_BYTES + BP_BYTES + W2P_BYTES);

  hipMemsetAsync(Xp, 0, XP_BYTES, stream);
  k_pad_transpose<<<dim3(43, 32, 16), dim3(32, 8), 0, stream>>>(fmap, Xp);
  k_pack_bfrag<<<dim3(2304), dim3(256), 0, stream>>>(W1, Bp);
  k_pack_w2<<<dim3(256), dim3(256), 0, stream>>>(W2, W2p);
  k_conv1<<<dim3(512), dim3(256), 0, stream>>>(Xp, Bp, b1, x1);
  k_conv2<<<dim3(12, 1, 16), dim3(256), 0, stream>>>(x1, W2p, b2, out);
}

// Round 15
// 242.931 us; speedup vs baseline: 1.3831x; 1.3831x over previous
//
#include <hip/hip_runtime.h>
#include <stdint.h>

#define HW   1369      // 37*37 output pixels
#define QW   39        // padded row width
#define QP   1616      // padded plane rows per (b) in Xp
#define QT   1536      // q rows in x1 (per batch)
#define CIN  1024
#define CMID 512
#define KTOT 9216      // 9 * 1024
#define NTIL 144       // K-tiles: 16 cblocks(64) * 9 taps, cblock-major tap-inner
#define ASL  12288     // A slot stride (elements): 192 x 64 (24 KB)
#define BB   24576     // B region base (elements) = 2 * ASL
#define BSL  8192      // B slot stride (elements): 128 x 64 (16 KB)

typedef float  f32x4  __attribute__((ext_vector_type(4)));
typedef __bf16 bf16x8 __attribute__((ext_vector_type(8)));

__device__ __forceinline__ uint16_t f2bf(float f) {
  uint32_t u = __float_as_uint(f);
  u += 0x7fffu + ((u >> 16) & 1u);
  return (uint16_t)(u >> 16);
}

// global -> LDS direct copy, 16B per lane. LDS dest = wave-uniform base + lane*16.
__device__ __forceinline__ void gll16(const void* g, void* l) {
  const __attribute__((address_space(1))) uint32_t* ga =
      (const __attribute__((address_space(1))) uint32_t*)(uintptr_t)g;
  __attribute__((address_space(3))) uint32_t* la =
      (__attribute__((address_space(3))) uint32_t*)(uint32_t)(uintptr_t)l;
  __builtin_amdgcn_global_load_lds(ga, la, 16, 0, 0);
}

// ---------- prep: zero ONLY the border rows of Xp (pad kernel writes the rest) ----------
// Unwritten-by-pad rows per batch: q in [0,40) U [1520,1616) U {q in [40,1520):
// q%39==0 (q=78..1482) or q%39==38 (q=77..1481)} -> 40 + 96 + 37 + 37 = 210 rows.
__global__ void k_zero_border(uint16_t* __restrict__ Xp) {
  const int bx = blockIdx.x;                 // 16 * 210
  const int batch = bx / 210, idx = bx - batch * 210;
  int q;
  if (idx < 40)       q = idx;
  else if (idx < 136) q = 1520 + (idx - 40);
  else {
    const int k = idx - 136;                 // 0..73
    const int pair = k >> 1;                 // 0..36
    q = (k & 1) ? ((pair + 1) * 39 + 38)     // 77, 116, ..., 1481
                : ((pair + 2) * 39);         // 78, 117, ..., 1482
  }
  uint64_t* p = (uint64_t*)(Xp + ((size_t)batch * QP + q) * CIN);
  p[threadIdx.x] = 0ull;                     // 256 thr x 8 B = 2048 B = full row
}

// ---------- prep: fmap [b][c][h][w] f32 -> Xp [b][q][c] bf16 (interior rows) ----------
__global__ void k_pad_transpose(const float* __restrict__ fmap, uint16_t* __restrict__ Xp) {
  __shared__ float t[32][33];
  const int b = blockIdx.z;
  const int c0 = blockIdx.y * 32;
  const int p0 = blockIdx.x * 32;
  const int tx = threadIdx.x, ty = threadIdx.y;
  const float* src = fmap + ((size_t)b * CIN + c0) * HW + p0;
#pragma unroll
  for (int i = 0; i < 4; ++i) {
    int cc = ty + i * 8;
    t[cc][tx] = (p0 + tx < HW) ? src[(size_t)cc * HW + tx] : 0.f;
  }
  __syncthreads();
#pragma unroll
  for (int i = 0; i < 4; ++i) {
    int pl = ty + i * 8;
    int p = p0 + pl;
    if (p < HW) {
      int h = p / 37, w = p - h * 37;
      int q = (h + 1) * QW + (w + 1);
      Xp[((size_t)b * QP + q) * CIN + c0 + tx] = f2bf(t[tx][pl]);
    }
  }
}

// ---------- prep: W1 [o][c][3][3] f32 -> Apk [o][r*1024+c] bf16 ----------
__global__ void k_pack_w1(const float* __restrict__ W1, uint16_t* __restrict__ Apk) {
  int idx = blockIdx.x * 256 + threadIdx.x;
  if (idx >= 512 * KTOT) return;
  int o = idx / KTOT, k = idx - o * KTOT;
  int r = k >> 10, c = k & 1023;
  Apk[idx] = f2bf(W1[((size_t)o * CIN + c) * 9 + r]);
}

// ---------- prep: W2 [120][512] f32 -> W2p [128][512] bf16 ----------
__global__ void k_pack_w2(const float* __restrict__ W2, uint16_t* __restrict__ W2p) {
  int idx = blockIdx.x * 256 + threadIdx.x;
  int j = idx >> 9, o = idx & 511;
  W2p[idx] = (j < 120) ? f2bf(W2[j * 512 + o]) : (uint16_t)0;
}

// ---------- conv1: implicit GEMM, 2 blocks/CU (r11 optimum, FROZEN) ----------
// Block = BM192 x BN128 x BK64, 4 waves (2M x 2N, wave 96x64), LDS 80KB
// (A 2x24KB + B 2x16KB). Grid = 512 = 2 blocks/CU. Cross-block pipe overlap:
// two independent barrier groups/CU (r6-r14: all single-group schedules hit
// the LDS+MFMA serialization wall; 2 groups = best measured 187us / 60% util).
// Stage t+1 into opposite slot; one vmcnt(0)+barrier per tile; plain C++ body.
// K-order: t = cblock*9 + tap (tap-inner, A panel L2-hot). T2 XOR swizzle.
__global__ __launch_bounds__(256, 2) void k_conv1(
    const uint16_t* __restrict__ Xp, const uint16_t* __restrict__ Apk,
    const float* __restrict__ b1, uint16_t* __restrict__ x1) {
  __shared__ __align__(16) uint16_t lds[2 * ASL + 2 * BSL];   // 81920 B

  const int tid  = threadIdx.x;
  const int wid  = tid >> 6, lane = tid & 63;
  const int lrow = lane & 15, lq = lane >> 4;
  const int wm   = wid >> 1,  wn = wid & 1;           // 2M x 2N

  // grid: 512 blocks = 8 XCDs x 64, mt-major within XCD (4 nt consecutive)
  const int bid = blockIdx.x;
  const int g   = (bid & 7) * 64 + (bid >> 3);
  const int mt  = g >> 2, nt = g & 3;
  const int batch = mt >> 3, qb = (mt & 7) * 192;
  const int o0 = nt * 128;
  const uint16_t* Xb = Xp + (size_t)batch * QP * CIN;

  // fragment-read swizzled column offsets (elements); lds_byte = glob_byte ^ ((row&7)<<4)
  const int xorb    = (lrow & 7) << 4;
  const int col_el0 = ((lq * 16) ^ xorb) >> 1;   // kk=0
  const int col_el1 = col_el0 ^ 32;              // kk=1 (toggle byte bit 6)

  // staging: 256 threads; srow = tid>>3 (0..31), pre-swizzled source column
  const int scol = ((tid & 7) ^ ((tid >> 3) & 7)) * 8;   // elements
  const int srow = tid >> 3;

  f32x4 acc[6][4] = {};

#define STAGE(u) do {                                                                 \
    if ((u) < NTIL) {                                                                 \
      const int cb_  = (u) / 9;                                                       \
      const int tap_ = (u) - cb_ * 9;                                                 \
      const int off_ = (tap_ / 3) * QW + tap_ % 3;                                    \
      const int c0_  = cb_ << 6;                                                      \
      uint16_t* sa = lds + ((u) & 1) * ASL;                                           \
      uint16_t* sb = lds + BB + ((u) & 1) * BSL;                                      \
      _Pragma("unroll")                                                               \
      for (int j = 0; j < 6; ++j)                                                     \
        gll16(Xb + (size_t)(qb + off_ + j * 32 + srow) * CIN + c0_ + scol,            \
              sa + (j * 256 + wid * 64) * 8);                                         \
      _Pragma("unroll")                                                               \
      for (int j = 0; j < 4; ++j)                                                     \
        gll16(Apk + (size_t)(o0 + j * 32 + srow) * KTOT + (tap_ << 10) + c0_ + scol,  \
              sb + (j * 256 + wid * 64) * 8);                                         \
    }                                                                                 \
  } while (0)

  // prologue: stage tile 0
  STAGE(0);

  for (int t = 0; t < NTIL; ++t) {
    const uint16_t* As = lds + (t & 1) * ASL;
    const uint16_t* Bs = lds + BB + (t & 1) * BSL;
    asm volatile("s_waitcnt vmcnt(0)" ::: "memory");   // stage(t) landed
    asm volatile("s_barrier" ::: "memory");            // all waves see slot t
    __builtin_amdgcn_sched_barrier(0);
    STAGE(t + 1);                                      // opposite slot, no WAR

    bf16x8 av0[6], av1[6], bv0[4], bv1[4];
#pragma unroll
    for (int n = 0; n < 4; ++n) {
      const uint16_t* br = Bs + (wn * 64 + n * 16 + lrow) * 64;
      bv0[n] = *(const bf16x8*)(br + col_el0);
      bv1[n] = *(const bf16x8*)(br + col_el1);
    }
#pragma unroll
    for (int m = 0; m < 6; ++m) {
      const uint16_t* ar = As + (wm * 96 + m * 16 + lrow) * 64;
      av0[m] = *(const bf16x8*)(ar + col_el0);
      av1[m] = *(const bf16x8*)(ar + col_el1);
    }
    __builtin_amdgcn_s_setprio(1);
#pragma unroll
    for (int m = 0; m < 6; ++m)
#pragma unroll
      for (int n = 0; n < 4; ++n)
        acc[m][n] = __builtin_amdgcn_mfma_f32_16x16x32_bf16(av0[m], bv0[n], acc[m][n], 0, 0, 0);
#pragma unroll
    for (int m = 0; m < 6; ++m)
#pragma unroll
      for (int n = 0; n < 4; ++n)
        acc[m][n] = __builtin_amdgcn_mfma_f32_16x16x32_bf16(av1[m], bv1[n], acc[m][n], 0, 0, 0);
    __builtin_amdgcn_s_setprio(0);
  }

  // epilogue: bias + ReLU6 -> x1 bf16
  const int qr = lq * 4;
#pragma unroll
  for (int n = 0; n < 4; ++n) {
    const int o = o0 + wn * 64 + n * 16 + lrow;
    const float bias = b1[o];
#pragma unroll
    for (int m = 0; m < 6; ++m) {
#pragma unroll
      for (int v = 0; v < 4; ++v) {
        const int q = qb + wm * 96 + m * 16 + qr + v;
        float x = acc[m][n][v] + bias;
        x = fminf(fmaxf(x, 0.f), 6.f);
        x1[((size_t)batch * QT + q) * CMID + o] = f2bf(x);
      }
    }
  }
#undef STAGE
}

// ---------- conv2: out[b][h][w][j] = sum_o x1[q][o] * W2[j][o] + b2[j] ----------
// BM=64 (grid 24x16=384 blocks, 1.5/CU) for better grid fill than BM=128's 192.
__global__ __launch_bounds__(256, 2) void k_conv2(
    const uint16_t* __restrict__ x1, const uint16_t* __restrict__ W2p,
    const float* __restrict__ b2, float* __restrict__ out) {
  __shared__ __align__(16) uint16_t lA[64 * 64];
  __shared__ __align__(16) uint16_t lB[128 * 64];
  const int tid = threadIdx.x;
  const int wid = tid >> 6, lane = tid & 63;
  const int b = blockIdx.z, q0 = blockIdx.x * 64;
  const uint16_t* Ab = x1 + (size_t)b * QT * CMID;
  const int wm = wid >> 1, wn = wid & 1;
  const int lrow = lane & 15, lk = (lane >> 4) * 8;
  f32x4 acc[2][4] = {};

  for (int kt = 0; kt < 8; ++kt) {
    const int c0 = kt << 6;
#pragma unroll
    for (int i = 0; i < 2; ++i) {     // A: 64 rows x 8 chunks = 512
      int wb = i * 256 + wid * 64;
      int chunk = wb + lane;
      int row = chunk >> 3, ch = chunk & 7;
      gll16(Ab + (size_t)(q0 + row) * CMID + c0 + ch * 8, lA + wb * 8);
    }
#pragma unroll
    for (int i = 0; i < 4; ++i) {     // B: 128 rows x 8 chunks = 1024
      int wb = i * 256 + wid * 64;
      int chunk = wb + lane;
      int row = chunk >> 3, ch = chunk & 7;
      gll16(W2p + (size_t)row * CMID + c0 + ch * 8, lB + wb * 8);
    }
    __syncthreads();
#pragma unroll
    for (int kk = 0; kk < 2; ++kk) {
      bf16x8 av[2], bv[4];
#pragma unroll
      for (int mi = 0; mi < 2; ++mi)
        av[mi] = *(const bf16x8*)(lA + (wm * 32 + mi * 16 + lrow) * 64 + kk * 32 + lk);
#pragma unroll
      for (int ni = 0; ni < 4; ++ni)
        bv[ni] = *(const bf16x8*)(lB + (wn * 64 + ni * 16 + lrow) * 64 + kk * 32 + lk);
#pragma unroll
      for (int mi = 0; mi < 2; ++mi)
#pragma unroll
        for (int ni = 0; ni < 4; ++ni)
          acc[mi][ni] = __builtin_amdgcn_mfma_f32_16x16x32_bf16(av[mi], bv[ni], acc[mi][ni], 0, 0, 0);
    }
    __syncthreads();
  }

  const int qr = (lane >> 4) * 4;
#pragma unroll
  for (int ni = 0; ni < 4; ++ni) {
    int j = wn * 64 + ni * 16 + lrow;
    if (j < 120) {
      float bias = b2[j];
#pragma unroll
      for (int mi = 0; mi < 2; ++mi) {
#pragma unroll
        for (int v = 0; v < 4; ++v) {
          int q = q0 + wm * 32 + mi * 16 + qr + v;
          int h = q / QW, w = q - h * QW;
          if (h < 37 && w < 37) {
            out[((size_t)b * HW + h * 37 + w) * 120 + j] = acc[mi][ni][v] + bias;
          }
        }
      }
    }
  }
}

extern "C" void kernel_launch(void* const* d_in, const int* in_sizes, int n_in,
                              void* d_out, int out_size, void* d_ws, size_t ws_size,
                              hipStream_t stream) {
  const float* fmap = (const float*)d_in[0];
  const float* W1   = (const float*)d_in[1];
  const float* b1   = (const float*)d_in[2];
  const float* W2   = (const float*)d_in[3];
  const float* b2   = (const float*)d_in[4];
  float* out = (float*)d_out;

  uint8_t* ws = (uint8_t*)d_ws;
  const size_t XP_BYTES  = (size_t)16 * QP * CIN * 2;   // 52,953,088
  const size_t W1P_BYTES = (size_t)512 * KTOT * 2;      //  9,437,184
  const size_t W2P_BYTES = (size_t)128 * 512 * 2;       //    131,072
  uint16_t* Xp  = (uint16_t*)ws;
  uint16_t* Apk = (uint16_t*)(ws + XP_BYTES);
  uint16_t* W2p = (uint16_t*)(ws + XP_BYTES + W1P_BYTES);
  uint16_t* x1  = (uint16_t*)(ws + XP_BYTES + W1P_BYTES + W2P_BYTES);

  k_zero_border<<<dim3(16 * 210), dim3(256), 0, stream>>>(Xp);
  k_pad_transpose<<<dim3(43, 32, 16), dim3(32, 8), 0, stream>>>(fmap, Xp);
  k_pack_w1<<<dim3((512 * KTOT + 255) / 256), dim3(256), 0, stream>>>(W1, Apk);
  k_pack_w2<<<dim3(256), dim3(256), 0, stream>>>(W2, W2p);
  k_conv1<<<dim3(512), dim3(256), 0, stream>>>(Xp, Apk, b1, x1);
  k_conv2<<<dim3(24, 1, 16), dim3(256), 0, stream>>>(x1, W2p, b2, out);
}

// Round 16
// 230.825 us; speedup vs baseline: 1.4556x; 1.0524x over previous
//
#include <hip/hip_runtime.h>
#include <stdint.h>

#define HW   1369      // 37*37 output pixels
#define QW   39        // padded row width
#define QP2  1648      // padded plane rows per (b) in Xp (1616 used + panel slack)
#define QT   1536      // q rows in x1 (per batch)
#define CIN  1024
#define CMID 512
#define KTOT 9216      // 9 * 1024
#define NTIL 144       // K-tiles: 16 cblocks(64) * 9 taps, cblock-major tap-inner
#define PANEL 18432    // A panel: 288 rows x 64 el = 36 KB (single-buffered)
#define BSL  8192      // B slot stride (elements): 128 x 64 (16 KB), double-buffered

typedef float  f32x4  __attribute__((ext_vector_type(4)));
typedef __bf16 bf16x8 __attribute__((ext_vector_type(8)));

__device__ __forceinline__ uint16_t f2bf(float f) {
  uint32_t u = __float_as_uint(f);
  u += 0x7fffu + ((u >> 16) & 1u);
  return (uint16_t)(u >> 16);
}

// global -> LDS direct copy, 16B per lane. LDS dest = wave-uniform base + lane*16.
__device__ __forceinline__ void gll16(const void* g, void* l) {
  const __attribute__((address_space(1))) uint32_t* ga =
      (const __attribute__((address_space(1))) uint32_t*)(uintptr_t)g;
  __attribute__((address_space(3))) uint32_t* la =
      (__attribute__((address_space(3))) uint32_t*)(uint32_t)(uintptr_t)l;
  __builtin_amdgcn_global_load_lds(ga, la, 16, 0, 0);
}

// ---------- prep: zero ONLY the border rows of Xp (pad kernel writes interior) ----------
// Rows never written by pad, per batch: [0,40) U [1520,1616) U {q%39==0 in 78..1482}
// U {q%39==38 in 77..1481} = 210 rows. Rows 1616..1647 are staged into panel rows
// >=272 but never read by fragments -> no zeroing needed.
__global__ void k_zero_border(uint16_t* __restrict__ Xp) {
  const int bx = blockIdx.x;                 // 16 * 210
  const int batch = bx / 210, idx = bx - batch * 210;
  int q;
  if (idx < 40)       q = idx;
  else if (idx < 136) q = 1520 + (idx - 40);
  else {
    const int k = idx - 136;
    const int pair = k >> 1;
    q = (k & 1) ? ((pair + 1) * 39 + 38) : ((pair + 2) * 39);
  }
  uint64_t* p = (uint64_t*)(Xp + ((size_t)batch * QP2 + q) * CIN);
  p[threadIdx.x] = 0ull;
}

// ---------- prep: fmap [b][c][h][w] f32 -> Xp [b][q][c] bf16 (interior rows) ----------
__global__ void k_pad_transpose(const float* __restrict__ fmap, uint16_t* __restrict__ Xp) {
  __shared__ float t[32][33];
  const int b = blockIdx.z;
  const int c0 = blockIdx.y * 32;
  const int p0 = blockIdx.x * 32;
  const int tx = threadIdx.x, ty = threadIdx.y;
  const float* src = fmap + ((size_t)b * CIN + c0) * HW + p0;
#pragma unroll
  for (int i = 0; i < 4; ++i) {
    int cc = ty + i * 8;
    t[cc][tx] = (p0 + tx < HW) ? src[(size_t)cc * HW + tx] : 0.f;
  }
  __syncthreads();
#pragma unroll
  for (int i = 0; i < 4; ++i) {
    int pl = ty + i * 8;
    int p = p0 + pl;
    if (p < HW) {
      int h = p / 37, w = p - h * 37;
      int q = (h + 1) * QW + (w + 1);
      Xp[((size_t)b * QP2 + q) * CIN + c0 + tx] = f2bf(t[tx][pl]);
    }
  }
}

// ---------- prep: W1 [o][c][3][3] f32 -> Apk [o][r*1024+c] bf16 ----------
__global__ void k_pack_w1(const float* __restrict__ W1, uint16_t* __restrict__ Apk) {
  int idx = blockIdx.x * 256 + threadIdx.x;
  if (idx >= 512 * KTOT) return;
  int o = idx / KTOT, k = idx - o * KTOT;
  int r = k >> 10, c = k & 1023;
  Apk[idx] = f2bf(W1[((size_t)o * CIN + c) * 9 + r]);
}

// ---------- prep: W2 [120][512] f32 -> W2p [128][512] bf16 ----------
__global__ void k_pack_w2(const float* __restrict__ W2, uint16_t* __restrict__ W2p) {
  int idx = blockIdx.x * 256 + threadIdx.x;
  int j = idx >> 9, o = idx & 511;
  W2p[idx] = (j < 120) ? f2bf(W2[j * 512 + o]) : (uint16_t)0;
}

// ---------- conv1: r11 structure + tap-reuse A panel (writes amortized 9x) ----------
// Block 192x128, 4 waves 2M x 2N (wave 96x64), grid 512 = 2 blocks/CU.
// A: single 288x64 panel (36KB) staged once per 9-tile cblock group; taps read
//    row-shifted views (off = (tap/3)*39 + tap%3). Panel(cb+1) staged after a
//    trailing barrier at tap8 (all waves' reads drained by their MFMA lgkm waits).
// B: r11 double-buffered LDS slots, staged per tile, vmcnt(0)+barrier per tile.
// LDS 68KB/block; per-CU staging writes drop 11.5 -> 5.8 MB.
__global__ __launch_bounds__(256, 2) void k_conv1(
    const uint16_t* __restrict__ Xp, const uint16_t* __restrict__ Apk,
    const float* __restrict__ b1, uint16_t* __restrict__ x1) {
  __shared__ __align__(16) uint16_t lds[PANEL + 2 * BSL];   // 69632 B

  const int tid  = threadIdx.x;
  const int wid  = tid >> 6, lane = tid & 63;
  const int lrow = lane & 15, lq = lane >> 4;
  const int wm   = wid >> 1,  wn = wid & 1;           // 2M x 2N

  // grid: 512 blocks = 8 XCDs x 64, mt-major within XCD (4 nt consecutive)
  const int bid = blockIdx.x;
  const int g   = (bid & 7) * 64 + (bid >> 3);
  const int mt  = g >> 2, nt = g & 3;
  const int batch = mt >> 3, qb = (mt & 7) * 192;
  const int o0 = nt * 128;
  const uint16_t* Xb = Xp + (size_t)batch * QP2 * CIN;

  // B fragment-read swizzled cols (B rows: row&7 = lrow&7)
  const int xorb    = (lrow & 7) << 4;
  const int col_el0 = ((lq * 16) ^ xorb) >> 1;
  const int col_el1 = col_el0 ^ 32;

  // B staging (r11 mapping): srow = tid>>3 (0..31), pre-swizzled source col
  const int scol = ((tid & 7) ^ ((tid >> 3) & 7)) * 8;
  const int srow = tid >> 3;

  // panel staging: per call each wave writes 8 rows (1KB); row&7 = sR8
  const int sR8 = lane >> 3;
  const int sc8 = ((lane & 7) ^ sR8) * 8;

  f32x4 acc[6][4] = {};

#define STPAN(cb1, call) do {                                                         \
    if ((cb1) < 16) {                                                                 \
      const int c0_ = (cb1) << 6;                                                     \
      const int Rb  = (call) * 32 + wid * 8;                                          \
      gll16(Xb + (size_t)(qb + Rb + sR8) * CIN + c0_ + sc8, lds + Rb * 64);           \
    }                                                                                 \
  } while (0)

#define STAGEB(cbv, tapv, slot) do {                                                  \
    const int c0_ = (cbv) << 6;                                                       \
    uint16_t* sb = lds + PANEL + (slot) * BSL;                                        \
    _Pragma("unroll")                                                                 \
    for (int j = 0; j < 4; ++j)                                                       \
      gll16(Apk + (size_t)(o0 + j * 32 + srow) * KTOT + ((tapv) << 10) + c0_ + scol,  \
            sb + (j * 256 + wid * 64) * 8);                                           \
  } while (0)

  // prologue: panel(0) (9 calls) + B(0) into slot 0
#pragma unroll
  for (int c = 0; c < 9; ++c) STPAN(0, c);
  STAGEB(0, 0, 0);

  for (int cb = 0; cb < 16; ++cb) {
#pragma unroll
    for (int tap = 0; tap < 9; ++tap) {
      const int t = cb * 9 + tap;
      asm volatile("s_waitcnt vmcnt(0)" ::: "memory");   // B(t) (+panel at tap0) landed
      asm volatile("s_barrier" ::: "memory");
      __builtin_amdgcn_sched_barrier(0);
      if (tap < 8)           STAGEB(cb, tap + 1, (t + 1) & 1);
      else if (cb + 1 < 16)  STAGEB(cb + 1, 0, (t + 1) & 1);

      const int off_ = (tap / 3) * QW + tap % 3;
      const int r7   = (off_ + lrow) & 7;
      const int ce0  = ((lq * 16) ^ (r7 << 4)) >> 1;
      const int ce1  = ce0 ^ 32;
      const uint16_t* Bs = lds + PANEL + (t & 1) * BSL;

      bf16x8 av0[6], av1[6], bv0[4], bv1[4];
#pragma unroll
      for (int n = 0; n < 4; ++n) {
        const uint16_t* br = Bs + (wn * 64 + n * 16 + lrow) * 64;
        bv0[n] = *(const bf16x8*)(br + col_el0);
        bv1[n] = *(const bf16x8*)(br + col_el1);
      }
#pragma unroll
      for (int m = 0; m < 6; ++m) {
        const uint16_t* ar = lds + (off_ + wm * 96 + m * 16 + lrow) * 64;
        av0[m] = *(const bf16x8*)(ar + ce0);
        av1[m] = *(const bf16x8*)(ar + ce1);
      }
      __builtin_amdgcn_s_setprio(1);
#pragma unroll
      for (int m = 0; m < 6; ++m)
#pragma unroll
        for (int n = 0; n < 4; ++n)
          acc[m][n] = __builtin_amdgcn_mfma_f32_16x16x32_bf16(av0[m], bv0[n], acc[m][n], 0, 0, 0);
#pragma unroll
      for (int m = 0; m < 6; ++m)
#pragma unroll
        for (int n = 0; n < 4; ++n)
          acc[m][n] = __builtin_amdgcn_mfma_f32_16x16x32_bf16(av1[m], bv1[n], acc[m][n], 0, 0, 0);
      __builtin_amdgcn_s_setprio(0);

      if (tap == 8) {
        // all waves' panel reads are drained (MFMA lgkm waits) before this barrier
        asm volatile("s_barrier" ::: "memory");
        __builtin_amdgcn_sched_barrier(0);
        if (cb + 1 < 16) {
#pragma unroll
          for (int c = 0; c < 9; ++c) STPAN(cb + 1, c);
        }
      }
    }
  }

  // epilogue: bias + ReLU6 -> x1 bf16
  const int qr = lq * 4;
#pragma unroll
  for (int n = 0; n < 4; ++n) {
    const int o = o0 + wn * 64 + n * 16 + lrow;
    const float bias = b1[o];
#pragma unroll
    for (int m = 0; m < 6; ++m) {
#pragma unroll
      for (int v = 0; v < 4; ++v) {
        const int q = qb + wm * 96 + m * 16 + qr + v;
        float x = acc[m][n][v] + bias;
        x = fminf(fmaxf(x, 0.f), 6.f);
        x1[((size_t)batch * QT + q) * CMID + o] = f2bf(x);
      }
    }
  }
#undef STAGEB
#undef STPAN
}

// ---------- conv2: out[b][h][w][j] = sum_o x1[q][o] * W2[j][o] + b2[j] ----------
__global__ __launch_bounds__(256, 2) void k_conv2(
    const uint16_t* __restrict__ x1, const uint16_t* __restrict__ W2p,
    const float* __restrict__ b2, float* __restrict__ out) {
  __shared__ __align__(16) uint16_t lA[64 * 64];
  __shared__ __align__(16) uint16_t lB[128 * 64];
  const int tid = threadIdx.x;
  const int wid = tid >> 6, lane = tid & 63;
  const int b = blockIdx.z, q0 = blockIdx.x * 64;
  const uint16_t* Ab = x1 + (size_t)b * QT * CMID;
  const int wm = wid >> 1, wn = wid & 1;
  const int lrow = lane & 15, lk = (lane >> 4) * 8;
  f32x4 acc[2][4] = {};

  for (int kt = 0; kt < 8; ++kt) {
    const int c0 = kt << 6;
#pragma unroll
    for (int i = 0; i < 2; ++i) {
      int wb = i * 256 + wid * 64;
      int chunk = wb + lane;
      int row = chunk >> 3, ch = chunk & 7;
      gll16(Ab + (size_t)(q0 + row) * CMID + c0 + ch * 8, lA + wb * 8);
    }
#pragma unroll
    for (int i = 0; i < 4; ++i) {
      int wb = i * 256 + wid * 64;
      int chunk = wb + lane;
      int row = chunk >> 3, ch = chunk & 7;
      gll16(W2p + (size_t)row * CMID + c0 + ch * 8, lB + wb * 8);
    }
    __syncthreads();
#pragma unroll
    for (int kk = 0; kk < 2; ++kk) {
      bf16x8 av[2], bv[4];
#pragma unroll
      for (int mi = 0; mi < 2; ++mi)
        av[mi] = *(const bf16x8*)(lA + (wm * 32 + mi * 16 + lrow) * 64 + kk * 32 + lk);
#pragma unroll
      for (int ni = 0; ni < 4; ++ni)
        bv[ni] = *(const bf16x8*)(lB + (wn * 64 + ni * 16 + lrow) * 64 + kk * 32 + lk);
#pragma unroll
      for (int mi = 0; mi < 2; ++mi)
#pragma unroll
        for (int ni = 0; ni < 4; ++ni)
          acc[mi][ni] = __builtin_amdgcn_mfma_f32_16x16x32_bf16(av[mi], bv[ni], acc[mi][ni], 0, 0, 0);
    }
    __syncthreads();
  }

  const int qr = (lane >> 4) * 4;
#pragma unroll
  for (int ni = 0; ni < 4; ++ni) {
    int j = wn * 64 + ni * 16 + lrow;
    if (j < 120) {
      float bias = b2[j];
#pragma unroll
      for (int mi = 0; mi < 2; ++mi) {
#pragma unroll
        for (int v = 0; v < 4; ++v) {
          int q = q0 + wm * 32 + mi * 16 + qr + v;
          int h = q / QW, w = q - h * QW;
          if (h < 37 && w < 37) {
            out[((size_t)b * HW + h * 37 + w) * 120 + j] = acc[mi][ni][v] + bias;
          }
        }
      }
    }
  }
}

extern "C" void kernel_launch(void* const* d_in, const int* in_sizes, int n_in,
                              void* d_out, int out_size, void* d_ws, size_t ws_size,
                              hipStream_t stream) {
  const float* fmap = (const float*)d_in[0];
  const float* W1   = (const float*)d_in[1];
  const float* b1   = (const float*)d_in[2];
  const float* W2   = (const float*)d_in[3];
  const float* b2   = (const float*)d_in[4];
  float* out = (float*)d_out;

  uint8_t* ws = (uint8_t*)d_ws;
  const size_t XP_BYTES  = (size_t)16 * QP2 * CIN * 2;  // 54,001,664
  const size_t W1P_BYTES = (size_t)512 * KTOT * 2;      //  9,437,184
  const size_t W2P_BYTES = (size_t)128 * 512 * 2;       //    131,072
  uint16_t* Xp  = (uint16_t*)ws;
  uint16_t* Apk = (uint16_t*)(ws + XP_BYTES);
  uint16_t* W2p = (uint16_t*)(ws + XP_BYTES + W1P_BYTES);
  uint16_t* x1  = (uint16_t*)(ws + XP_BYTES + W1P_BYTES + W2P_BYTES);

  k_zero_border<<<dim3(16 * 210), dim3(256), 0, stream>>>(Xp);
  k_pad_transpose<<<dim3(43, 32, 16), dim3(32, 8), 0, stream>>>(fmap, Xp);
  k_pack_w1<<<dim3((512 * KTOT + 255) / 256), dim3(256), 0, stream>>>(W1, Apk);
  k_pack_w2<<<dim3(256), dim3(256), 0, stream>>>(W2, W2p);
  k_conv1<<<dim3(512), dim3(256), 0, stream>>>(Xp, Apk, b1, x1);
  k_conv2<<<dim3(24, 1, 16), dim3(256), 0, stream>>>(x1, W2p, b2, out);
}